// Round 5
// baseline (892.120 us; speedup 1.0000x reference)
//
#include <hip/hip_runtime.h>

// CausalSelfAttention: B=8, S=2048, D=512, fp32 in/out, Q=K=V=x, no scale.
// Round 5: uniform-work, barrier-free flash attention with direct global
// fragment reads.
//   - Frag-packed operands in ws (round-3 layout, verified):
//       Kf[b][kg:128][db:16][lane:64][8]  elem = x[b][16*kg+l15][32*db+8*quad+j]
//       Vf[b][dg:32][kb:64][lane:64][8]   elem = x[b][32*kb+8*quad+j][16*dg+l15]
//   - attn: 512 blocks x 4 waves, block = stripe pair (p, 127-p) = exactly 65
//     32-key tiles for every p -> all 2048 waves uniform (~16 tiles each),
//     all co-resident (2 blocks/CU, 2 waves/SIMD). K/V/Q frags read straight
//     from L2 (1KB coalesced wave loads); NO __syncthreads in the K-loop.
//     Split stripes merge (m,l,O) partials via a 32KB LDS accumulator in the
//     epilogue. batch = bid&7 pins each batch to one XCD's L2.
//   - pack: 1024 blocks, 16-row panels, contiguous 2KB HBM row reads.
// ws: [0,16MiB) Kf, [16MiB,32MiB) Vf.

#define S_LEN 2048
#define D_DIM 512
#define BATCH_ELEMS (S_LEN * D_DIM)

typedef short s16x8 __attribute__((ext_vector_type(8)));
typedef float f32x4 __attribute__((ext_vector_type(4)));

__device__ __forceinline__ unsigned short f2b_rne(float f) {
  unsigned int u = __float_as_uint(f);
  return (unsigned short)((u + 0x7FFFu + ((u >> 16) & 1u)) >> 16);
}
__device__ __forceinline__ unsigned short f2b_fast(float f) {
  return (unsigned short)((__float_as_uint(f) + 0x8000u) >> 16);
}

template <int CTRL>
__device__ __forceinline__ float dppf(float x) {
  return __uint_as_float((unsigned)__builtin_amdgcn_update_dpp(
      0, (int)__float_as_uint(x), CTRL, 0xF, 0xF, true));
}
__device__ __forceinline__ float red16_max(float v) {
  v = fmaxf(v, dppf<0xB1>(v));   // xor 1
  v = fmaxf(v, dppf<0x4E>(v));   // xor 2
  v = fmaxf(v, dppf<0x124>(v));  // row_ror:4
  v = fmaxf(v, dppf<0x128>(v));  // row_ror:8
  return v;
}
__device__ __forceinline__ float red16_sum(float v) {
  v += dppf<0xB1>(v);
  v += dppf<0x4E>(v);
  v += dppf<0x124>(v);
  v += dppf<0x128>(v);
  return v;
}

// ---------------------------------------------------------------------------
// Pack: 1024 blocks x 256 thr; block = one 16-row stripe (full D).
// Reads are contiguous 2KB per row (perfect HBM streaming).
// ---------------------------------------------------------------------------
__global__ __launch_bounds__(256)
void pack_kernel(const float* __restrict__ x,
                 unsigned short* __restrict__ Kf,
                 unsigned short* __restrict__ Vf) {
  __shared__ unsigned short A[16 * 516];  // [row][col], stride 516
  __shared__ unsigned short T[512 * 24];  // [col][row], stride 24
  const int bid = blockIdx.x;
  const int b = bid >> 7;    // batch
  const int g = bid & 127;   // stripe
  const int tid = threadIdx.x;

  // phase 1: load + convert -> A
  #pragma unroll
  for (int i = 0; i < 4; ++i) {
    int flat = i * 256 + tid;          // 0..1023
    int row = flat >> 6;               // 0..15
    int cg = flat & 63;                // 8-col group
    const float* src = x + ((size_t)(b * S_LEN + g * 16 + row)) * D_DIM + cg * 8;
    float4 v0 = *(const float4*)src;
    float4 v1 = *(const float4*)(src + 4);
    s16x8 o;
    o[0] = (short)f2b_rne(v0.x); o[1] = (short)f2b_rne(v0.y);
    o[2] = (short)f2b_rne(v0.z); o[3] = (short)f2b_rne(v0.w);
    o[4] = (short)f2b_rne(v1.x); o[5] = (short)f2b_rne(v1.y);
    o[6] = (short)f2b_rne(v1.z); o[7] = (short)f2b_rne(v1.w);
    *(s16x8*)&A[row * 516 + cg * 8] = o;
  }
  __syncthreads();

  // phase 2a: Kf frag writes from A (1KB contiguous per 64-thread group)
  #pragma unroll
  for (int i = 0; i < 4; ++i) {
    int flat = i * 256 + tid;
    int db = flat >> 6;                // 0..15
    int lane = flat & 63;
    int l15 = lane & 15, quad = lane >> 4;
    s16x8 val = *(const s16x8*)&A[l15 * 516 + db * 32 + quad * 8];
    *(s16x8*)(Kf + (size_t)b * BATCH_ELEMS + ((size_t)(g * 16 + db)) * 512 + lane * 8) = val;
  }
  // phase 2b: transpose A -> T (4x4 micro-blocks)
  #pragma unroll
  for (int i = 0; i < 2; ++i) {
    int mb = i * 256 + tid;            // 0..511
    int mr = mb & 3;                   // rows 4mr..4mr+3
    int mc = mb >> 2;                  // cols 4mc..4mc+3
    ushort4 a0 = *(const ushort4*)&A[(4 * mr + 0) * 516 + 4 * mc];
    ushort4 a1 = *(const ushort4*)&A[(4 * mr + 1) * 516 + 4 * mc];
    ushort4 a2 = *(const ushort4*)&A[(4 * mr + 2) * 516 + 4 * mc];
    ushort4 a3 = *(const ushort4*)&A[(4 * mr + 3) * 516 + 4 * mc];
    ushort4 t0; t0.x = a0.x; t0.y = a1.x; t0.z = a2.x; t0.w = a3.x;
    ushort4 t1; t1.x = a0.y; t1.y = a1.y; t1.z = a2.y; t1.w = a3.y;
    ushort4 t2; t2.x = a0.z; t2.y = a1.z; t2.z = a2.z; t2.w = a3.z;
    ushort4 t3; t3.x = a0.w; t3.y = a1.w; t3.z = a2.w; t3.w = a3.w;
    *(ushort4*)&T[(4 * mc + 0) * 24 + 4 * mr] = t0;
    *(ushort4*)&T[(4 * mc + 1) * 24 + 4 * mr] = t1;
    *(ushort4*)&T[(4 * mc + 2) * 24 + 4 * mr] = t2;
    *(ushort4*)&T[(4 * mc + 3) * 24 + 4 * mr] = t3;
  }
  __syncthreads();

  // phase 3: Vf half-frag writes from T (512B contiguous per 32-thread group)
  #pragma unroll
  for (int i = 0; i < 4; ++i) {
    int flat = i * 256 + tid;          // 0..1023
    int dg = flat >> 5;                // 0..31
    int lane32 = flat & 31;
    int ql = lane32 >> 4;              // local quad 0/1
    int l15 = lane32 & 15;
    s16x8 val = *(const s16x8*)&T[(16 * dg + l15) * 24 + 8 * ql];
    int gq = (g & 1) * 2 + ql;         // global quad within kb
    int kb = g >> 1;
    *(s16x8*)(Vf + (size_t)b * BATCH_ELEMS + ((size_t)(dg * 64 + kb)) * 512 +
              (gq * 16 + l15) * 8) = val;
  }
}

// ---------------------------------------------------------------------------
// Flash segment for 16-row stripe over tiles [kt0,kt1), direct global frags.
// MFMA 16x16x32: A[m=l15][k=quad*8+j], B[k=quad*8+j][n=l15],
// C/D: col=l15, row=quad*4+reg.
// ---------------------------------------------------------------------------
__device__ __forceinline__ void flash_seg(
    const unsigned short* __restrict__ KfB,
    const unsigned short* __restrict__ VfB,
    int stripe, int kt0, int kt1, bool maskLast,
    unsigned short* __restrict__ Pw, int lane,
    f32x4 (&O)[32], float (&m)[4], float (&l)[4]) {
  if (kt0 >= kt1) return;
  const int l15 = lane & 15, quad = lane >> 4;

  s16x8 qf[16];
  {
    const unsigned short* qb = KfB + ((size_t)stripe * 16) * 512 + lane * 8;
    #pragma unroll
    for (int db = 0; db < 16; ++db) qf[db] = *(const s16x8*)(qb + db * 512);
  }

  for (int kt = kt0; kt < kt1; ++kt) {
    // ---- QK^T: S[16 rows][32 keys] ----
    f32x4 sacc[2];
    sacc[0] = (f32x4){0.f, 0.f, 0.f, 0.f};
    sacc[1] = (f32x4){0.f, 0.f, 0.f, 0.f};
    const unsigned short* kp = KfB + (size_t)kt * 16384 + lane * 8;
    #pragma unroll 4
    for (int db = 0; db < 16; ++db) {
      s16x8 k0 = *(const s16x8*)(kp + db * 512);
      s16x8 k1 = *(const s16x8*)(kp + 8192 + db * 512);
      sacc[0] = __builtin_amdgcn_mfma_f32_16x16x32_bf16(qf[db], k0, sacc[0], 0, 0, 0);
      sacc[1] = __builtin_amdgcn_mfma_f32_16x16x32_bf16(qf[db], k1, sacc[1], 0, 0, 0);
    }
    if (maskLast && kt == kt1 - 1) {
      #pragma unroll
      for (int kg2 = 0; kg2 < 2; ++kg2)
        #pragma unroll
        for (int r = 0; r < 4; ++r) {
          int key = kt * 32 + kg2 * 16 + l15;
          int row = stripe * 16 + quad * 4 + r;
          if (key > row) sacc[kg2][r] = -3e38f;
        }
    }

    // ---- online softmax (registers + DPP) ----
    float mt[4], alpha[4];
    #pragma unroll
    for (int r = 0; r < 4; ++r)
      mt[r] = red16_max(fmaxf(sacc[0][r], sacc[1][r]));
    bool needAny = (mt[0] > m[0]) | (mt[1] > m[1]) | (mt[2] > m[2]) | (mt[3] > m[3]);
    unsigned long long bal = __ballot(needAny);
    if (bal) {
      #pragma unroll
      for (int r = 0; r < 4; ++r) {
        float mn = fmaxf(m[r], mt[r]);
        alpha[r] = __expf(m[r] - mn);
        m[r] = mn;
      }
    } else {
      #pragma unroll
      for (int r = 0; r < 4; ++r) alpha[r] = 1.0f;
    }
    float p[2][4];
    #pragma unroll
    for (int kg2 = 0; kg2 < 2; ++kg2)
      #pragma unroll
      for (int r = 0; r < 4; ++r) p[kg2][r] = __expf(sacc[kg2][r] - m[r]);
    #pragma unroll
    for (int r = 0; r < 4; ++r)
      l[r] = l[r] * alpha[r] + red16_sum(p[0][r] + p[1][r]);

    // ---- P: C-layout -> A-layout via wave-private LDS ----
    #pragma unroll
    for (int kg2 = 0; kg2 < 2; ++kg2)
      #pragma unroll
      for (int r = 0; r < 4; ++r)
        Pw[(quad * 4 + r) * 40 + kg2 * 16 + l15] = f2b_fast(p[kg2][r]);
    s16x8 pa = *(const s16x8*)&Pw[l15 * 40 + quad * 8];

    if (bal) {
      #pragma unroll
      for (int n = 0; n < 32; ++n)
        #pragma unroll
        for (int r = 0; r < 4; ++r) O[n][r] *= alpha[r];
    }

    // ---- PV: O[16 rows][512] += P(16x32) * V(32x512) ----
    const unsigned short* vp = VfB + (size_t)kt * 512 + lane * 8;
    #pragma unroll 4
    for (int dg = 0; dg < 32; ++dg) {
      s16x8 vf = *(const s16x8*)(vp + (size_t)dg * 32768);
      O[dg] = __builtin_amdgcn_mfma_f32_16x16x32_bf16(pa, vf, O[dg], 0, 0, 0);
    }
  }
}

// ---------------------------------------------------------------------------
// attn: 512 blocks x 256 thr. Block = (batch, pair p): stripes sL=p, sH=127-p,
// TL+TH = 65 tiles, cut {0,17,33,49,65} across 4 waves.
// ---------------------------------------------------------------------------
__global__ __launch_bounds__(256, 2)
void attn_kernel(const unsigned short* __restrict__ Kf,
                 const unsigned short* __restrict__ Vf,
                 float* __restrict__ out) {
  __shared__ float accO[32 * 256];          // [dg][lane*4], 32 KB
  __shared__ float accM[16], accL[16];
  __shared__ unsigned short Plds[4][16 * 40];

  const int bid = blockIdx.x;
  const int bat = bid & 7;                  // XCD-pinned batch
  const int p = bid >> 3;                   // 0..63
  const int sL = p, sH = 127 - p;
  const int TL = (p >> 1) + 1;              // 1..32
  const int TH = 65 - TL;                   // 33..64
  const int tid = threadIdx.x;
  const int w = tid >> 6;
  const int lane = tid & 63;
  const int l15 = lane & 15, quad = lane >> 4;
  const unsigned short* KfB = Kf + (size_t)bat * BATCH_ELEMS;
  const unsigned short* VfB = Vf + (size_t)bat * BATCH_ELEMS;
  unsigned short* Pw = Plds[w];

  const int cuts[5] = {0, 17, 33, 49, 65};
  const int c_lo = cuts[w], c_hi = cuts[w + 1];
  const bool lsplit = (TL > 17);            // block-uniform
  const bool w0h = (TL < 17);               // block-uniform

  f32x4 O[32];
  float m[4], l[4];
  #pragma unroll
  for (int n = 0; n < 32; ++n) O[n] = (f32x4){0.f, 0.f, 0.f, 0.f};
  #pragma unroll
  for (int r = 0; r < 4; ++r) { m[r] = -3e38f; l[r] = 0.f; }

  // ---- L segment (only waves 0,1 can have one) ----
  if (c_lo < TL) {
    int e = (c_hi < TL) ? c_hi : TL;
    flash_seg(KfB, VfB, sL, c_lo, e, e == TL, Pw, lane, O, m, l);
    if (w == 0 && !lsplit) {
      // sole owner: normalize + write out stripe L now
      float invl[4];
      #pragma unroll
      for (int r = 0; r < 4; ++r) invl[r] = 1.0f / l[r];
      float* ob = out + ((size_t)(bat * S_LEN + sL * 16)) * D_DIM;
      #pragma unroll
      for (int dg = 0; dg < 32; ++dg)
        #pragma unroll
        for (int r = 0; r < 4; ++r)
          ob[(size_t)(quad * 4 + r) * D_DIM + dg * 16 + l15] = O[dg][r] * invl[r];
    } else if (w == 1) {
      // dump L partial to acc (sole writer until epilogue barrier)
      #pragma unroll
      for (int dg = 0; dg < 32; ++dg)
        *(f32x4*)&accO[dg * 256 + lane * 4] = O[dg];
      if (l15 == 0) {
        #pragma unroll
        for (int r = 0; r < 4; ++r) {
          accM[quad * 4 + r] = m[r];
          accL[quad * 4 + r] = l[r];
        }
      }
    }
    // w==0 && lsplit: keep L partial in registers until epilogue
  }

  // ---- H segment ----
  const bool keepL = (w == 0) && lsplit;    // w0 preserves L regs (has no H)
  {
    int h0 = ((c_lo > TL) ? c_lo : TL) - TL;
    int h1 = c_hi - TL;
    if (h1 > h0 && !keepL) {
      #pragma unroll
      for (int n = 0; n < 32; ++n) O[n] = (f32x4){0.f, 0.f, 0.f, 0.f};
      #pragma unroll
      for (int r = 0; r < 4; ++r) { m[r] = -3e38f; l[r] = 0.f; }
      flash_seg(KfB, VfB, sH, h0, h1, h1 == TH, Pw, lane, O, m, l);
    }
  }

  // ================= epilogue: merges (block-uniform barriers) ==============
  if (lsplit) {
    __syncthreads();  // w1's L dump visible
    if (w == 0) {     // merge reg L-partial with acc, normalize, write out L
      float fA[4], fB[4], invl[4];
      #pragma unroll
      for (int r = 0; r < 4; ++r) {
        float mA = accM[quad * 4 + r], lA = accL[quad * 4 + r];
        float mp = fmaxf(mA, m[r]);
        fA[r] = __expf(mA - mp);
        fB[r] = __expf(m[r] - mp);
        invl[r] = 1.0f / (lA * fA[r] + l[r] * fB[r]);
      }
      float* ob = out + ((size_t)(bat * S_LEN + sL * 16)) * D_DIM;
      #pragma unroll
      for (int dg = 0; dg < 32; ++dg) {
        f32x4 a = *(const f32x4*)&accO[dg * 256 + lane * 4];
        #pragma unroll
        for (int r = 0; r < 4; ++r)
          ob[(size_t)(quad * 4 + r) * D_DIM + dg * 16 + l15] =
              (a[r] * fA[r] + O[dg][r] * fB[r]) * invl[r];
      }
    }
    __syncthreads();  // acc free for H merge
  }

  // H merge: contributors = {w0 if w0h} + {w1, w2, w3}
  if ((w0h && w == 0) || (!w0h && w == 1)) {
    #pragma unroll
    for (int dg = 0; dg < 32; ++dg)
      *(f32x4*)&accO[dg * 256 + lane * 4] = O[dg];
    if (l15 == 0) {
      #pragma unroll
      for (int r = 0; r < 4; ++r) {
        accM[quad * 4 + r] = m[r];
        accL[quad * 4 + r] = l[r];
      }
    }
  }
  __syncthreads();
  if (w0h) {
    if (w == 1) {  // merge into acc
      float fA[4], fB[4], mn[4], ln[4];
      #pragma unroll
      for (int r = 0; r < 4; ++r) {
        float mA = accM[quad * 4 + r], lA = accL[quad * 4 + r];
        mn[r] = fmaxf(mA, m[r]);
        fA[r] = __expf(mA - mn[r]);
        fB[r] = __expf(m[r] - mn[r]);
        ln[r] = lA * fA[r] + l[r] * fB[r];
      }
      #pragma unroll
      for (int dg = 0; dg < 32; ++dg) {
        f32x4 a = *(const f32x4*)&accO[dg * 256 + lane * 4];
        #pragma unroll
        for (int r = 0; r < 4; ++r) a[r] = a[r] * fA[r] + O[dg][r] * fB[r];
        *(f32x4*)&accO[dg * 256 + lane * 4] = a;
      }
      if (l15 == 0) {
        #pragma unroll
        for (int r = 0; r < 4; ++r) {
          accM[quad * 4 + r] = mn[r];
          accL[quad * 4 + r] = ln[r];
        }
      }
    }
    __syncthreads();
  }
  if (w == 2) {  // merge into acc
    float fA[4], fB[4], mn[4], ln[4];
    #pragma unroll
    for (int r = 0; r < 4; ++r) {
      float mA = accM[quad * 4 + r], lA = accL[quad * 4 + r];
      mn[r] = fmaxf(mA, m[r]);
      fA[r] = __expf(mA - mn[r]);
      fB[r] = __expf(m[r] - mn[r]);
      ln[r] = lA * fA[r] + l[r] * fB[r];
    }
    #pragma unroll
    for (int dg = 0; dg < 32; ++dg) {
      f32x4 a = *(const f32x4*)&accO[dg * 256 + lane * 4];
      #pragma unroll
      for (int r = 0; r < 4; ++r) a[r] = a[r] * fA[r] + O[dg][r] * fB[r];
      *(f32x4*)&accO[dg * 256 + lane * 4] = a;
    }
    if (l15 == 0) {
      #pragma unroll
      for (int r = 0; r < 4; ++r) {
        accM[quad * 4 + r] = mn[r];
        accL[quad * 4 + r] = ln[r];
      }
    }
  }
  __syncthreads();
  if (w == 3) {  // final merge + normalize + write out stripe H
    float fA[4], fB[4], invl[4];
    #pragma unroll
    for (int r = 0; r < 4; ++r) {
      float mA = accM[quad * 4 + r], lA = accL[quad * 4 + r];
      float mp = fmaxf(mA, m[r]);
      fA[r] = __expf(mA - mp);
      fB[r] = __expf(m[r] - mp);
      invl[r] = 1.0f / (lA * fA[r] + l[r] * fB[r]);
    }
    float* ob = out + ((size_t)(bat * S_LEN + sH * 16)) * D_DIM;
    #pragma unroll
    for (int dg = 0; dg < 32; ++dg) {
      f32x4 a = *(const f32x4*)&accO[dg * 256 + lane * 4];
      #pragma unroll
      for (int r = 0; r < 4; ++r)
        ob[(size_t)(quad * 4 + r) * D_DIM + dg * 16 + l15] =
            (a[r] * fA[r] + O[dg][r] * fB[r]) * invl[r];
    }
  }
}

extern "C" void kernel_launch(void* const* d_in, const int* in_sizes, int n_in,
                              void* d_out, int out_size, void* d_ws, size_t ws_size,
                              hipStream_t stream) {
  (void)in_sizes; (void)n_in; (void)out_size; (void)ws_size;
  const float* x = (const float*)d_in[0];
  float* out = (float*)d_out;
  unsigned short* Kf = (unsigned short*)d_ws;                         // 16 MiB
  unsigned short* Vf = (unsigned short*)((char*)d_ws + (16u << 20));  // 16 MiB
  pack_kernel<<<1024, 256, 0, stream>>>(x, Kf, Vf);
  attn_kernel<<<512, 256, 0, stream>>>(Kf, Vf, out);
}

// Round 7
// 530.571 us; speedup vs baseline: 1.6814x; 1.6814x over previous
//
#include <hip/hip_runtime.h>

// CausalSelfAttention: B=8, S=2048, D=512, fp32 in/out, Q=K=V=x, no scale.
// Round 7: round-6 design + the missing accumulator reset (r6 bug: wave 0 in
// the !lsplit case ran its H segment with stripe L's O/lacc still loaded).
//   Fixed-shift softmax c_i=|x_i|^2 -> additive partials; uniform key-split
//   (65 tiles cut {0,17,33,49,65} over stripes p / 127-p across 4 waves);
//   zero main-loop barriers; direct global frag reads from L2.
//   Kf[b][kg:128][db:16][lane:64][8]  elem = x[b][16*kg+l15][32*db+8*q+j]
//   Vf[b][dg:32][kb:64][lane:64][8]   elem = x[b][32*kb+8*q+j][16*dg+l15]
// ws: [0,16MiB) Kf, [16MiB,32MiB) Vf.

#define S_LEN 2048
#define D_DIM 512
#define BATCH_ELEMS (S_LEN * D_DIM)

typedef short s16x8 __attribute__((ext_vector_type(8)));
typedef float f32x4 __attribute__((ext_vector_type(4)));

__device__ __forceinline__ unsigned short f2b_rne(float f) {
  unsigned int u = __float_as_uint(f);
  return (unsigned short)((u + 0x7FFFu + ((u >> 16) & 1u)) >> 16);
}
__device__ __forceinline__ unsigned short f2b_fast(float f) {
  return (unsigned short)((__float_as_uint(f) + 0x8000u) >> 16);
}

template <int CTRL>
__device__ __forceinline__ float dppf(float x) {
  return __uint_as_float((unsigned)__builtin_amdgcn_update_dpp(
      0, (int)__float_as_uint(x), CTRL, 0xF, 0xF, true));
}
__device__ __forceinline__ float red16_sum(float v) {
  v += dppf<0xB1>(v);   // xor 1
  v += dppf<0x4E>(v);   // xor 2
  v += dppf<0x124>(v);  // row_ror:4
  v += dppf<0x128>(v);  // row_ror:8
  return v;
}

// ---------------------------------------------------------------------------
// Pack: 512 blocks x 256 thr; block = (batch, 32-row band u).
// ---------------------------------------------------------------------------
__global__ __launch_bounds__(256)
void pack_kernel(const float* __restrict__ x,
                 unsigned short* __restrict__ Kf,
                 unsigned short* __restrict__ Vf) {
  __shared__ unsigned short A[32 * 520];
  __shared__ unsigned short T[512 * 40];
  const int bid = blockIdx.x;
  const int u = bid & 63, b = bid >> 6;
  const int tid = threadIdx.x;

  // phase 1: load + convert -> A  (each row = contiguous 2KB HBM read)
  #pragma unroll
  for (int i = 0; i < 4; ++i) {
    int flat = i * 256 + tid;          // 0..1023
    int rl = flat >> 5;                // 0..31
    int cg = flat & 31;                // 16-col group
    const float* src = x + ((size_t)(b * S_LEN + u * 32 + rl)) * D_DIM + cg * 16;
    float4 v0 = *(const float4*)src;
    float4 v1 = *(const float4*)(src + 4);
    float4 v2 = *(const float4*)(src + 8);
    float4 v3 = *(const float4*)(src + 12);
    s16x8 o0, o1;
    o0[0] = (short)f2b_rne(v0.x); o0[1] = (short)f2b_rne(v0.y);
    o0[2] = (short)f2b_rne(v0.z); o0[3] = (short)f2b_rne(v0.w);
    o0[4] = (short)f2b_rne(v1.x); o0[5] = (short)f2b_rne(v1.y);
    o0[6] = (short)f2b_rne(v1.z); o0[7] = (short)f2b_rne(v1.w);
    o1[0] = (short)f2b_rne(v2.x); o1[1] = (short)f2b_rne(v2.y);
    o1[2] = (short)f2b_rne(v2.z); o1[3] = (short)f2b_rne(v2.w);
    o1[4] = (short)f2b_rne(v3.x); o1[5] = (short)f2b_rne(v3.y);
    o1[6] = (short)f2b_rne(v3.z); o1[7] = (short)f2b_rne(v3.w);
    *(s16x8*)&A[rl * 520 + cg * 16] = o0;
    *(s16x8*)&A[rl * 520 + cg * 16 + 8] = o1;
  }
  __syncthreads();

  // phase 2a: Kf frags for stripes 2u, 2u+1 (1KB per 64-thread group)
  #pragma unroll
  for (int i = 0; i < 8; ++i) {
    int flat = i * 256 + tid;          // 0..2047
    int frag = flat >> 6;              // 0..31
    int lane = flat & 63;
    int h = frag >> 4, db = frag & 15;
    int l15 = lane & 15, q = lane >> 4;
    s16x8 val = *(const s16x8*)&A[(16 * h + l15) * 520 + db * 32 + q * 8];
    *(s16x8*)(Kf + (size_t)b * BATCH_ELEMS +
              ((size_t)((2 * u + h) * 16 + db)) * 512 + lane * 8) = val;
  }
  // phase 2b: transpose A -> T (4x4 micro-blocks)
  #pragma unroll
  for (int i = 0; i < 4; ++i) {
    int mb = i * 256 + tid;            // 0..1023
    int mr = mb & 7;
    int mc = mb >> 3;                  // 0..127
    ushort4 a0 = *(const ushort4*)&A[(4 * mr + 0) * 520 + 4 * mc];
    ushort4 a1 = *(const ushort4*)&A[(4 * mr + 1) * 520 + 4 * mc];
    ushort4 a2 = *(const ushort4*)&A[(4 * mr + 2) * 520 + 4 * mc];
    ushort4 a3 = *(const ushort4*)&A[(4 * mr + 3) * 520 + 4 * mc];
    ushort4 t0; t0.x = a0.x; t0.y = a1.x; t0.z = a2.x; t0.w = a3.x;
    ushort4 t1; t1.x = a0.y; t1.y = a1.y; t1.z = a2.y; t1.w = a3.y;
    ushort4 t2; t2.x = a0.z; t2.y = a1.z; t2.z = a2.z; t2.w = a3.z;
    ushort4 t3; t3.x = a0.w; t3.y = a1.w; t3.z = a2.w; t3.w = a3.w;
    *(ushort4*)&T[(4 * mc + 0) * 40 + 4 * mr] = t0;
    *(ushort4*)&T[(4 * mc + 1) * 40 + 4 * mr] = t1;
    *(ushort4*)&T[(4 * mc + 2) * 40 + 4 * mr] = t2;
    *(ushort4*)&T[(4 * mc + 3) * 40 + 4 * mr] = t3;
  }
  __syncthreads();

  // phase 3: Vf frags, kb = u (1KB per 64-thread group)
  #pragma unroll
  for (int i = 0; i < 8; ++i) {
    int flat = i * 256 + tid;
    int dg = flat >> 6;                // 0..31
    int lane = flat & 63;
    int l15 = lane & 15, q = lane >> 4;
    s16x8 val = *(const s16x8*)&T[(16 * dg + l15) * 40 + q * 8];
    *(s16x8*)(Vf + (size_t)b * BATCH_ELEMS +
              ((size_t)(dg * 64 + u)) * 512 + lane * 8) = val;
  }
}

// ---------------------------------------------------------------------------
// Flash segment with fixed shift c = |q_row|^2 (computed from qf in-register).
// MFMA 16x16x32: A[m=l15][k=q*8+j], B[k=q*8+j][n=l15], C/D: col=l15, row=q*4+r.
// ---------------------------------------------------------------------------
__device__ __forceinline__ void flash_seg(
    const unsigned short* __restrict__ KfB,
    const unsigned short* __restrict__ VfB,
    int stripe, int kt0, int kt1, bool maskLast,
    unsigned short* __restrict__ Pw, float* __restrict__ cbw, int lane,
    f32x4 (&O)[32], float (&lacc)[4]) {
  const int l15 = lane & 15, quad = lane >> 4;

  s16x8 qf[16];
  {
    const unsigned short* qb = KfB + ((size_t)stripe * 16) * 512 + lane * 8;
    #pragma unroll
    for (int db = 0; db < 16; ++db) qf[db] = *(const s16x8*)(qb + db * 512);
  }
  // c_row = sum of squares of the (bf16) Q row
  float cpart = 0.f;
  #pragma unroll
  for (int db = 0; db < 16; ++db)
    #pragma unroll
    for (int j = 0; j < 8; ++j) {
      float v = __uint_as_float(((unsigned)(unsigned short)qf[db][j]) << 16);
      cpart = fmaf(v, v, cpart);
    }
  cpart += __shfl_xor(cpart, 16);
  cpart += __shfl_xor(cpart, 32);
  if (quad == 0) cbw[l15] = cpart;           // wave-private
  f32x4 c4 = *(const f32x4*)&cbw[quad * 4];  // c for rows quad*4+r

  for (int kt = kt0; kt < kt1; ++kt) {
    // ---- QK^T: S[16 rows][32 keys] ----
    f32x4 s0 = (f32x4){0.f, 0.f, 0.f, 0.f};
    f32x4 s1 = (f32x4){0.f, 0.f, 0.f, 0.f};
    const unsigned short* kp = KfB + (size_t)kt * 16384 + lane * 8;
    #pragma unroll 4
    for (int db = 0; db < 16; ++db) {
      s16x8 k0 = *(const s16x8*)(kp + db * 512);
      s16x8 k1 = *(const s16x8*)(kp + 8192 + db * 512);
      s0 = __builtin_amdgcn_mfma_f32_16x16x32_bf16(qf[db], k0, s0, 0, 0, 0);
      s1 = __builtin_amdgcn_mfma_f32_16x16x32_bf16(qf[db], k1, s1, 0, 0, 0);
    }
    // ---- P = exp(S - c), accumulate row-sum partials, stash bf16 P ----
    const bool diag = maskLast && (kt == kt1 - 1);
    #pragma unroll
    for (int r = 0; r < 4; ++r) {
      float d0 = fminf(s0[r] - c4[r], 60.f);
      float d1 = fminf(s1[r] - c4[r], 60.f);
      if (diag) {
        int row = stripe * 16 + quad * 4 + r;
        if (kt * 32 + l15 > row) d0 = -3e38f;
        if (kt * 32 + 16 + l15 > row) d1 = -3e38f;
      }
      float p0 = __expf(d0), p1 = __expf(d1);
      lacc[r] += p0 + p1;
      Pw[(quad * 4 + r) * 40 + l15] = f2b_fast(p0);
      Pw[(quad * 4 + r) * 40 + 16 + l15] = f2b_fast(p1);
    }
    s16x8 pa = *(const s16x8*)&Pw[l15 * 40 + quad * 8];

    // ---- PV: O[16 rows][512] += P(16x32) * V(32x512) ----
    const unsigned short* vp = VfB + (size_t)kt * 512 + lane * 8;
    #pragma unroll 4
    for (int dg = 0; dg < 32; ++dg) {
      s16x8 vf = *(const s16x8*)(vp + (size_t)dg * 32768);
      O[dg] = __builtin_amdgcn_mfma_f32_16x16x32_bf16(pa, vf, O[dg], 0, 0, 0);
    }
  }
}

// ---------------------------------------------------------------------------
// attn: 512 blocks x 256 thr (4 waves).
// ---------------------------------------------------------------------------
__global__ __launch_bounds__(256, 2)
void attn_kernel(const unsigned short* __restrict__ Kf,
                 const unsigned short* __restrict__ Vf,
                 float* __restrict__ out) {
  __shared__ float bufO[2][32 * 256];   // [L/H][dg][lane*4], 2 x 32 KB
  __shared__ float lbuf[2][16];
  __shared__ unsigned short Plds[4][16 * 40];
  __shared__ float cb[4][16];

  const int bid = blockIdx.x;
  const int bat = bid & 7;
  const int p = bid >> 3;               // 0..63
  const int sL = p, sH = 127 - p;
  const int TL = (p >> 1) + 1;          // 1..32
  const int TH = 65 - TL;               // 33..64
  const int tid = threadIdx.x;
  const int w = tid >> 6;
  const int lane = tid & 63;
  const int l15 = lane & 15, quad = lane >> 4;
  const unsigned short* KfB = Kf + (size_t)bat * BATCH_ELEMS;
  const unsigned short* VfB = Vf + (size_t)bat * BATCH_ELEMS;

  const int cuts[5] = {0, 17, 33, 49, 65};
  const int c_lo = cuts[w], c_hi = cuts[w + 1];
  const bool hasL = c_lo < TL;
  const int Lend = (c_hi < TL) ? c_hi : TL;
  const bool hasH = c_hi > TL;
  const int h0 = ((c_lo > TL) ? c_lo : TL) - TL;
  const int h1 = c_hi - TL;
  const int firstH = (TL < 17) ? 0 : 1;  // block-uniform
  const bool lsplit = (TL >= 18);        // block-uniform

  f32x4 O[32];
  float lacc[4];
  #pragma unroll
  for (int n = 0; n < 32; ++n) O[n] = (f32x4){0.f, 0.f, 0.f, 0.f};
  #pragma unroll
  for (int r = 0; r < 4; ++r) lacc[r] = 0.f;

  if (hasL) {  // only waves 0,1 ever have an L segment
    flash_seg(KfB, VfB, sL, c_lo, Lend, Lend == TL, Plds[w], cb[w], lane, O, lacc);
    float lred[4];
    #pragma unroll
    for (int r = 0; r < 4; ++r) lred[r] = red16_sum(lacc[r]);
    if (w == 0 && !lsplit) {
      // sole owner: normalize + write L now, then RESET for the H segment
      // (r6 bug: missing reset contaminated stripe H for TL<17 blocks)
      float* ob = out + ((size_t)(bat * S_LEN + sL * 16)) * D_DIM;
      #pragma unroll
      for (int dg = 0; dg < 32; ++dg)
        #pragma unroll
        for (int r = 0; r < 4; ++r)
          ob[(size_t)(quad * 4 + r) * D_DIM + dg * 16 + l15] = O[dg][r] / lred[r];
      #pragma unroll
      for (int n = 0; n < 32; ++n) O[n] = (f32x4){0.f, 0.f, 0.f, 0.f};
      #pragma unroll
      for (int r = 0; r < 4; ++r) lacc[r] = 0.f;
    } else if (w == 1) {
      // dump L partial (additive merge later); then reset for H segment
      #pragma unroll
      for (int dg = 0; dg < 32; ++dg)
        *(f32x4*)&bufO[0][dg * 256 + lane * 4] = O[dg];
      if (l15 == 0) {
        #pragma unroll
        for (int r = 0; r < 4; ++r) lbuf[0][quad * 4 + r] = lred[r];
      }
      #pragma unroll
      for (int n = 0; n < 32; ++n) O[n] = (f32x4){0.f, 0.f, 0.f, 0.f};
      #pragma unroll
      for (int r = 0; r < 4; ++r) lacc[r] = 0.f;
    }
    // w==0 && lsplit: keep L partial in regs; w0 has no H segment in this case.
  }
  if (hasH) {
    flash_seg(KfB, VfB, sH, h0, h1, h1 == TH, Plds[w], cb[w], lane, O, lacc);
  }

  __syncthreads();  // B0: all main-loop work + w1's bufL dump visible

  float lred[4];
  #pragma unroll
  for (int r = 0; r < 4; ++r) lred[r] = red16_sum(lacc[r]);

  // P1: w0 finalizes split L; firstH wave stores bufH.
  if (lsplit && w == 0) {
    float* ob = out + ((size_t)(bat * S_LEN + sL * 16)) * D_DIM;
    #pragma unroll
    for (int dg = 0; dg < 32; ++dg) {
      f32x4 a = *(const f32x4*)&bufO[0][dg * 256 + lane * 4];
      #pragma unroll
      for (int r = 0; r < 4; ++r)
        ob[(size_t)(quad * 4 + r) * D_DIM + dg * 16 + l15] =
            (a[r] + O[dg][r]) / (lbuf[0][quad * 4 + r] + lred[r]);
    }
  }
  if (w == firstH) {
    #pragma unroll
    for (int dg = 0; dg < 32; ++dg)
      *(f32x4*)&bufO[1][dg * 256 + lane * 4] = O[dg];
    if (l15 == 0) {
      #pragma unroll
      for (int r = 0; r < 4; ++r) lbuf[1][quad * 4 + r] = lred[r];
    }
  }
  __syncthreads();  // B1
  if (firstH == 0 && w == 1) {
    #pragma unroll
    for (int dg = 0; dg < 32; ++dg) {
      f32x4 a = *(const f32x4*)&bufO[1][dg * 256 + lane * 4];
      #pragma unroll
      for (int r = 0; r < 4; ++r) a[r] += O[dg][r];
      *(f32x4*)&bufO[1][dg * 256 + lane * 4] = a;
    }
    if (l15 == 0) {
      #pragma unroll
      for (int r = 0; r < 4; ++r) lbuf[1][quad * 4 + r] += lred[r];
    }
  }
  __syncthreads();  // B2
  if (w == 2) {
    #pragma unroll
    for (int dg = 0; dg < 32; ++dg) {
      f32x4 a = *(const f32x4*)&bufO[1][dg * 256 + lane * 4];
      #pragma unroll
      for (int r = 0; r < 4; ++r) a[r] += O[dg][r];
      *(f32x4*)&bufO[1][dg * 256 + lane * 4] = a;
    }
    if (l15 == 0) {
      #pragma unroll
      for (int r = 0; r < 4; ++r) lbuf[1][quad * 4 + r] += lred[r];
    }
  }
  __syncthreads();  // B3
  if (w == 3) {  // final add + normalize + write H
    float* ob = out + ((size_t)(bat * S_LEN + sH * 16)) * D_DIM;
    #pragma unroll
    for (int dg = 0; dg < 32; ++dg) {
      f32x4 a = *(const f32x4*)&bufO[1][dg * 256 + lane * 4];
      #pragma unroll
      for (int r = 0; r < 4; ++r)
        ob[(size_t)(quad * 4 + r) * D_DIM + dg * 16 + l15] =
            (a[r] + O[dg][r]) / (lbuf[1][quad * 4 + r] + lred[r]);
    }
  }
}

extern "C" void kernel_launch(void* const* d_in, const int* in_sizes, int n_in,
                              void* d_out, int out_size, void* d_ws, size_t ws_size,
                              hipStream_t stream) {
  (void)in_sizes; (void)n_in; (void)out_size; (void)ws_size;
  const float* x = (const float*)d_in[0];
  float* out = (float*)d_out;
  unsigned short* Kf = (unsigned short*)d_ws;                         // 16 MiB
  unsigned short* Vf = (unsigned short*)((char*)d_ws + (16u << 20));  // 16 MiB
  pack_kernel<<<512, 256, 0, stream>>>(x, Kf, Vf);
  attn_kernel<<<512, 256, 0, stream>>>(Kf, Vf, out);
}